// Round 7
// baseline (167.747 us; speedup 1.0000x reference)
//
#include <hip/hip_runtime.h>
#include <stdint.h>

#define MDIM 1024
#define NDIM 2048
#define KDIM 2048
#define BETAC 0.9f
#define LAMC 1e-4f

typedef __attribute__((ext_vector_type(4))) float f32x4;
typedef __attribute__((ext_vector_type(8))) short s16x8;

typedef __attribute__((address_space(3))) unsigned int as3_u32;
typedef __attribute__((address_space(1))) unsigned int as1_u32;

__device__ __forceinline__ void gload_lds16(const void* g, const void* l) {
  __builtin_amdgcn_global_load_lds((const as1_u32*)(uintptr_t)g,
                                   (as3_u32*)(unsigned int)(uintptr_t)l, 16, 0, 0);
}

__device__ __forceinline__ unsigned short f2bf(float f) {
  union { float f; unsigned u; } x; x.f = f;
  unsigned r = x.u + 0x7fffu + ((x.u >> 16) & 1u);
  return (unsigned short)(r >> 16);
}

// ------- weight transposes (z=0,1) + x f32->bf16 convert (z=2) in one launch -------
__global__ __launch_bounds__(256) void prep_kernel(const float* __restrict__ Wz,
                                                   const float* __restrict__ Wx,
                                                   unsigned short* __restrict__ WzT,
                                                   unsigned short* __restrict__ WxT,
                                                   const float* __restrict__ x,
                                                   unsigned short* __restrict__ xb) {
  if (blockIdx.z == 2) {
    const int b = blockIdx.y * 64 + blockIdx.x;          // 0..4095
    const int t = threadIdx.y * 32 + threadIdx.x;        // 0..255
    if (t < 128) {
      const int i = b * 128 + t;                         // 4096*128 = MN/4
      f32x4 v = ((const f32x4*)x)[i];
      ushort4 o;
      o.x = f2bf(v[0]); o.y = f2bf(v[1]); o.z = f2bf(v[2]); o.w = f2bf(v[3]);
      ((ushort4*)xb)[i] = o;
    }
    return;
  }
  const float* W = blockIdx.z ? Wx : Wz;
  unsigned short* WT = blockIdx.z ? WxT : WzT;
  __shared__ float tile[32][33];
  const int tx = threadIdx.x, ty = threadIdx.y;
  const int col = blockIdx.x * 32 + tx;
  const int row0 = blockIdx.y * 32 + ty;
#pragma unroll
  for (int j = 0; j < 32; j += 8)
    tile[ty + j][tx] = W[(size_t)(row0 + j) * NDIM + col];
  __syncthreads();
  const int ocol = blockIdx.y * 32 + tx;
  const int orow0 = blockIdx.x * 32 + ty;
#pragma unroll
  for (int j = 0; j < 32; j += 8)
    WT[(size_t)(orow0 + j) * KDIM + ocol] = f2bf(tile[tx][ty + j]);
}

// ---------------- split-K GEMM: P[kz] = A(bf16 MxK/2) * BT(bf16 NxK/2)^T ----------------
// BM=64 BN=128 BK=64, KSPLIT=2, 256 threads (4 waves of 32x64).
// Triple-buffered 72KB LDS -> still 2 blocks/CU (144 <= 160KB), counted vmcnt(6)
// keeps one stage in flight across each barrier. XCD-aware 1-D block swizzle.
// K-start stagger: co-resident blocks (bid, bid+256) begin 8 K-tiles apart so
// their stage/drain phases interleave instead of aligning.
__global__ __launch_bounds__(256) void gemm_split_kernel(const unsigned short* __restrict__ A,
                                                         const unsigned short* __restrict__ BT,
                                                         float* __restrict__ P0,
                                                         float* __restrict__ P1) {
  __shared__ short As[3][64 * 64];    // 24 KB
  __shared__ short Bs[3][128 * 64];   // 48 KB

  const int bid = blockIdx.x;
  const int xcd = bid & 7;           // dispatch round-robins consecutive ids over XCDs
  const int slot = bid >> 3;         // 0..63 within XCD
  const int nb = slot & 15;          // n-block 0..15
  const int mb = (xcd >> 1) * 4 + (slot >> 4);  // m-block 0..15
  const int ksplit = xcd & 1;
  const int rot = ((bid >> 8) & 1) << 3;        // 0 or 8: co-resident phase offset

  const int tid = threadIdx.x;
  const int l = tid & 63;
  const int w = tid >> 6;
  const int wr = w >> 1, wc = w & 1;
  const int row0 = mb * 64;
  const int col0 = nb * 128;
  const int kbase = ksplit * (KDIM / 2);
  const int lrow = l & 15;
  const int lk8 = (l >> 4) * 8;
  const int wuni = (tid & ~63) * 8;  // wave-uniform LDS element base

  f32x4 acc[2][4];
#pragma unroll
  for (int mi = 0; mi < 2; mi++)
#pragma unroll
    for (int ni = 0; ni < 4; ni++) acc[mi][ni] = f32x4{0.f, 0.f, 0.f, 0.f};

  // stage one BK=64 tile (6 load-instructions): A 64x64 (512 slots), B 128x64 (1024)
  // slot u -> row r=u>>3, chunk c=((u&7)^(r&7))*8 (pre-swizzled source, linear LDS dest)
  auto stage = [&](int k0, int buf) {
#pragma unroll
    for (int p = 0; p < 2; p++) {
      int u = p * 256 + tid;
      int r = u >> 3;
      int c = ((u & 7) ^ (r & 7)) * 8;
      gload_lds16(A + (size_t)(row0 + r) * KDIM + k0 + c, &As[buf][p * 2048 + wuni]);
    }
#pragma unroll
    for (int p = 0; p < 4; p++) {
      int u = p * 256 + tid;
      int r = u >> 3;
      int c = ((u & 7) ^ (r & 7)) * 8;
      gload_lds16(BT + (size_t)(col0 + r) * KDIM + k0 + c, &Bs[buf][p * 2048 + wuni]);
    }
  };

  constexpr int NT = (KDIM / 2) / 64;  // 16
  auto ktile = [&](int t) { return kbase + (((t + rot) & 15) << 6); };

  stage(ktile(0), 0);
  stage(ktile(1), 1);
  asm volatile("s_waitcnt vmcnt(6)" ::: "memory");   // tile 0 landed, tile 1 in flight
  __syncthreads();

  int cur = 0;
  for (int t = 0; t < NT; ++t) {
    const int sb = (cur == 0) ? 2 : (cur - 1);       // (cur+2)%3
    if (t + 2 < NT) stage(ktile(t + 2), sb);

    const short* __restrict__ Acur = As[cur];
    const short* __restrict__ Bcur = Bs[cur];
#pragma unroll
    for (int ks = 0; ks < 2; ++ks) {
      const int kk = ks * 32 + lk8;
      s16x8 a[2], b[4];
#pragma unroll
      for (int mi = 0; mi < 2; mi++) {
        int rr = wr * 32 + mi * 16 + lrow;
        int sidx = (rr * 64 + kk) ^ ((rr & 7) << 3);
        a[mi] = *(const s16x8*)(&Acur[sidx]);
      }
#pragma unroll
      for (int ni = 0; ni < 4; ni++) {
        int rr = wc * 64 + ni * 16 + lrow;
        int sidx = (rr * 64 + kk) ^ ((rr & 7) << 3);
        b[ni] = *(const s16x8*)(&Bcur[sidx]);
      }
      __builtin_amdgcn_s_setprio(1);
#pragma unroll
      for (int mi = 0; mi < 2; mi++)
#pragma unroll
        for (int ni = 0; ni < 4; ni++)
          acc[mi][ni] = __builtin_amdgcn_mfma_f32_16x16x32_bf16(a[mi], b[ni], acc[mi][ni], 0, 0, 0);
      __builtin_amdgcn_s_setprio(0);
    }

    if (t + 2 < NT) {
      asm volatile("s_waitcnt vmcnt(6)" ::: "memory");  // tile t+1 landed, t+2 in flight
    } else if (t + 1 < NT) {
      asm volatile("s_waitcnt vmcnt(0)" ::: "memory");  // tail: only t+1 outstanding
    }
    __syncthreads();
    cur = (cur == 2) ? 0 : (cur + 1);
  }

  float* __restrict__ P = ksplit ? P1 : P0;
#pragma unroll
  for (int mi = 0; mi < 2; mi++) {
#pragma unroll
    for (int ni = 0; ni < 4; ni++) {
      const int col = col0 + wc * 64 + ni * 16 + lrow;
      const int rbase = row0 + wr * 32 + mi * 16 + (l >> 4) * 4;
#pragma unroll
      for (int j = 0; j < 4; j++)
        P[(size_t)(rbase + j) * NDIM + col] = acc[mi][ni][j];
    }
  }
}

// ---------------- fused per-row epilogue: combine partials + g + gamma + update ----------------
// MODE 0: xproj = P0+P1+bias; z1 = 0.9*tanh(xproj); writes xproj, z1, zb
// MODE 1: g = tanh(P0+P1+xproj) - z; z2 = z + 0.9g; writes g, z2, zb
// MODE 2: g, gamma(row), anderson update; writes g, znew, zb
// MODE 3: g, gamma(row), anderson update; writes d_out only
template <int MODE>
__global__ __launch_bounds__(256) void rowfused_kernel(const float* __restrict__ P0,
                                                       const float* __restrict__ P1,
                                                       const float* __restrict__ xp_or_bias,
                                                       const float* __restrict__ z,
                                                       const float* __restrict__ zp,
                                                       const float* __restrict__ gp,
                                                       float* __restrict__ gout,
                                                       float* __restrict__ zout,
                                                       unsigned short* __restrict__ zbout,
                                                       float* __restrict__ xpout) {
  const int row = blockIdx.x;
  const int tid = threadIdx.x;
  const size_t b4 = (size_t)row * (NDIM / 4);
  __shared__ float sn[4], sd[4];
  __shared__ float sga;

  int vi[2] = {tid, tid + 256};
  f32x4 gv[2], znv[2], zv[2], zpv[2], gpv[2];
  float num = 0.f, den = 0.f;

#pragma unroll
  for (int h = 0; h < 2; h++) {
    const size_t q = b4 + vi[h];
    f32x4 p0 = ((const f32x4*)P0)[q];
    f32x4 p1 = ((const f32x4*)P1)[q];
    f32x4 xb;
    if (MODE == 0) xb = ((const f32x4*)xp_or_bias)[vi[h]];   // bias (row-invariant)
    else xb = ((const f32x4*)xp_or_bias)[q];                 // xproj
    if (MODE != 0) zv[h] = ((const f32x4*)z)[q];
    if (MODE >= 2) {
      zpv[h] = ((const f32x4*)zp)[q];
      gpv[h] = ((const f32x4*)gp)[q];
    }
#pragma unroll
    for (int j = 0; j < 4; j++) {
      const float s = p0[j] + p1[j] + xb[j];
      if (MODE == 0) {
        const float z1 = BETAC * tanhf(s);
        gv[h][j] = s;      // xproj value to store
        znv[h][j] = z1;
      } else {
        const float g = tanhf(s) - zv[h][j];
        gv[h][j] = g;
        if (MODE == 1) znv[h][j] = zv[h][j] + BETAC * g;
        else {
          const float dg = g - gpv[h][j];
          num += dg * g;
          den += dg * dg;
        }
      }
    }
  }

  if (MODE >= 2) {
#pragma unroll
    for (int off = 32; off > 0; off >>= 1) {
      num += __shfl_down(num, off);
      den += __shfl_down(den, off);
    }
    if ((tid & 63) == 0) { sn[tid >> 6] = num; sd[tid >> 6] = den; }
    __syncthreads();
    if (tid == 0)
      sga = (sn[0] + sn[1] + sn[2] + sn[3]) / (sd[0] + sd[1] + sd[2] + sd[3] + LAMC);
    __syncthreads();
    const float ga = sga;
#pragma unroll
    for (int h = 0; h < 2; h++)
#pragma unroll
      for (int j = 0; j < 4; j++)
        znv[h][j] = zv[h][j] + BETAC * gv[h][j]
                  - ga * ((zv[h][j] - zpv[h][j]) + BETAC * (gv[h][j] - gpv[h][j]));
  }

#pragma unroll
  for (int h = 0; h < 2; h++) {
    const size_t q = b4 + vi[h];
    if (MODE == 0) ((f32x4*)xpout)[q] = gv[h];
    if (MODE == 1 || MODE == 2) ((f32x4*)gout)[q] = gv[h];
    ((f32x4*)zout)[q] = znv[h];
    if (MODE != 3) {
      ushort4 o;
      o.x = f2bf(znv[h][0]); o.y = f2bf(znv[h][1]);
      o.z = f2bf(znv[h][2]); o.w = f2bf(znv[h][3]);
      ((ushort4*)zbout)[q] = o;
    }
  }
}

extern "C" void kernel_launch(void* const* d_in, const int* in_sizes, int n_in,
                              void* d_out, int out_size, void* d_ws, size_t ws_size,
                              hipStream_t stream) {
  const float* x = (const float*)d_in[0];
  const float* Wz = (const float*)d_in[1];
  const float* Wx = (const float*)d_in[2];
  const float* bias = (const float*)d_in[3];

  const size_t MN = (size_t)MDIM * NDIM;
  const size_t KN = (size_t)KDIM * NDIM;
  char* ws = (char*)d_ws;
  size_t off = 0;
  auto alloc = [&](size_t bytes) -> void* {
    void* p = ws + off;
    off += (bytes + 255) & ~(size_t)255;
    return p;
  };
  unsigned short* WzT = (unsigned short*)alloc(KN * 2);
  unsigned short* WxT = (unsigned short*)alloc(KN * 2);
  unsigned short* xb = (unsigned short*)alloc(MN * 2);
  float* xproj = (float*)alloc(MN * 4);
  float* zA = (float*)alloc(MN * 4);
  float* zB = (float*)alloc(MN * 4);
  float* gA = (float*)alloc(MN * 4);
  float* gB = (float*)alloc(MN * 4);
  unsigned short* zb16 = (unsigned short*)alloc(MN * 2);
  float* P0 = (float*)alloc(MN * 4);
  float* P1 = (float*)alloc(MN * 4);
  (void)ws_size;

  const dim3 tb(32, 8);
  const dim3 pgrid(NDIM / 32, KDIM / 32, 3);
  const int ggrid = 512;   // 16n x 16m x 2ks, XCD-swizzled in-kernel

  prep_kernel<<<pgrid, tb, 0, stream>>>(Wz, Wx, WzT, WxT, x, xb);

  // iter 0: x_proj = x@Wx + b ; z1 = 0.9*tanh(x_proj)
  gemm_split_kernel<<<ggrid, 256, 0, stream>>>(xb, WxT, P0, P1);
  rowfused_kernel<0><<<MDIM, 256, 0, stream>>>(P0, P1, bias, nullptr, nullptr, nullptr,
                                               nullptr, zA, zb16, xproj);

  float* zc = zA;
  float* zp = zB;
  float* gc = gA;
  float* gp = gB;

  // iter 1: simple update
  gemm_split_kernel<<<ggrid, 256, 0, stream>>>(zb16, WzT, P0, P1);
  rowfused_kernel<1><<<MDIM, 256, 0, stream>>>(P0, P1, xproj, zc, nullptr, nullptr,
                                               gc, zp, zb16, nullptr);
  { float* t = zc; zc = zp; zp = t; }   // zc=z2, zp=z1
  { float* t = gc; gc = gp; gp = t; }   // gp=g1

  // iters 2..4: anderson updates
  for (int it = 2; it < 5; ++it) {
    gemm_split_kernel<<<ggrid, 256, 0, stream>>>(zb16, WzT, P0, P1);
    rowfused_kernel<2><<<MDIM, 256, 0, stream>>>(P0, P1, xproj, zc, zp, gp,
                                                 gc, zp, zb16, nullptr);
    { float* t = zc; zc = zp; zp = t; }
    { float* t = gc; gc = gp; gp = t; }
  }

  // iter 5: final anderson update straight to d_out
  gemm_split_kernel<<<ggrid, 256, 0, stream>>>(zb16, WzT, P0, P1);
  rowfused_kernel<3><<<MDIM, 256, 0, stream>>>(P0, P1, xproj, zc, zp, gp,
                                               nullptr, (float*)d_out, nullptr, nullptr);
}

// Round 8
// 162.243 us; speedup vs baseline: 1.0339x; 1.0339x over previous
//
#include <hip/hip_runtime.h>
#include <stdint.h>

#define MDIM 1024
#define NDIM 2048
#define KDIM 2048
#define BETAC 0.9f
#define LAMC 1e-4f

typedef __attribute__((ext_vector_type(4))) float f32x4;
typedef __attribute__((ext_vector_type(8))) short s16x8;

typedef __attribute__((address_space(3))) unsigned int as3_u32;
typedef __attribute__((address_space(1))) unsigned int as1_u32;

__device__ __forceinline__ void gload_lds16(const void* g, const void* l) {
  __builtin_amdgcn_global_load_lds((const as1_u32*)(uintptr_t)g,
                                   (as3_u32*)(unsigned int)(uintptr_t)l, 16, 0, 0);
}

__device__ __forceinline__ unsigned short f2bf(float f) {
  union { float f; unsigned u; } x; x.f = f;
  unsigned r = x.u + 0x7fffu + ((x.u >> 16) & 1u);
  return (unsigned short)(r >> 16);
}

// ------- weight transposes (z=0,1) + x f32->bf16 convert (z=2) in one launch -------
__global__ __launch_bounds__(256) void prep_kernel(const float* __restrict__ Wz,
                                                   const float* __restrict__ Wx,
                                                   unsigned short* __restrict__ WzT,
                                                   unsigned short* __restrict__ WxT,
                                                   const float* __restrict__ x,
                                                   unsigned short* __restrict__ xb) {
  if (blockIdx.z == 2) {
    const int b = blockIdx.y * 64 + blockIdx.x;          // 0..4095
    const int t = threadIdx.y * 32 + threadIdx.x;        // 0..255
    if (t < 128) {
      const int i = b * 128 + t;                         // 4096*128 = MN/4
      f32x4 v = ((const f32x4*)x)[i];
      ushort4 o;
      o.x = f2bf(v[0]); o.y = f2bf(v[1]); o.z = f2bf(v[2]); o.w = f2bf(v[3]);
      ((ushort4*)xb)[i] = o;
    }
    return;
  }
  const float* W = blockIdx.z ? Wx : Wz;
  unsigned short* WT = blockIdx.z ? WxT : WzT;
  __shared__ float tile[32][33];
  const int tx = threadIdx.x, ty = threadIdx.y;
  const int col = blockIdx.x * 32 + tx;
  const int row0 = blockIdx.y * 32 + ty;
#pragma unroll
  for (int j = 0; j < 32; j += 8)
    tile[ty + j][tx] = W[(size_t)(row0 + j) * NDIM + col];
  __syncthreads();
  const int ocol = blockIdx.y * 32 + tx;
  const int orow0 = blockIdx.x * 32 + ty;
#pragma unroll
  for (int j = 0; j < 32; j += 8)
    WT[(size_t)(orow0 + j) * KDIM + ocol] = f2bf(tile[tx][ty + j]);
}

// ---------------- split-K GEMM: P[kz] = A(bf16 MxK/2) * BT(bf16 NxK/2)^T ----------------
// BM=64 BN=128 BK=64, KSPLIT=2, 256 threads (4 waves of 32x64).
// Triple-buffered 72KB LDS -> 2 blocks/CU (144 <= 160KB). Counted vmcnt(6): tile
// t+1's loads issued a full iteration earlier, so the per-iter wait pays only BW
// shortfall, never full latency. XCD-aware swizzle; NO k-stagger (it thrashed L2:
// per-XCD B k-half slice is exactly 4MB, only lockstep k-walk keeps it resident).
__global__ __launch_bounds__(256) void gemm_split_kernel(const unsigned short* __restrict__ A,
                                                         const unsigned short* __restrict__ BT,
                                                         float* __restrict__ P0,
                                                         float* __restrict__ P1) {
  __shared__ short As[3][64 * 64];    // 24 KB
  __shared__ short Bs[3][128 * 64];   // 48 KB

  const int bid = blockIdx.x;
  const int xcd = bid & 7;           // dispatch round-robins consecutive ids over XCDs
  const int slot = bid >> 3;         // 0..63 within XCD
  const int nb = slot & 15;          // n-block 0..15
  const int mb = (xcd >> 1) * 4 + (slot >> 4);  // m-block 0..15
  const int ksplit = xcd & 1;

  const int tid = threadIdx.x;
  const int l = tid & 63;
  const int w = tid >> 6;
  const int wr = w >> 1, wc = w & 1;
  const int row0 = mb * 64;
  const int col0 = nb * 128;
  const int kbase = ksplit * (KDIM / 2);
  const int lrow = l & 15;
  const int lk8 = (l >> 4) * 8;
  const int wuni = (tid & ~63) * 8;  // wave-uniform LDS element base

  f32x4 acc[2][4];
#pragma unroll
  for (int mi = 0; mi < 2; mi++)
#pragma unroll
    for (int ni = 0; ni < 4; ni++) acc[mi][ni] = f32x4{0.f, 0.f, 0.f, 0.f};

  // stage one BK=64 tile (6 load-instructions): A 64x64 (512 slots), B 128x64 (1024)
  // slot u -> row r=u>>3, chunk c=((u&7)^(r&7))*8 (pre-swizzled source, linear LDS dest)
  auto stage = [&](int k0, int buf) {
#pragma unroll
    for (int p = 0; p < 2; p++) {
      int u = p * 256 + tid;
      int r = u >> 3;
      int c = ((u & 7) ^ (r & 7)) * 8;
      gload_lds16(A + (size_t)(row0 + r) * KDIM + k0 + c, &As[buf][p * 2048 + wuni]);
    }
#pragma unroll
    for (int p = 0; p < 4; p++) {
      int u = p * 256 + tid;
      int r = u >> 3;
      int c = ((u & 7) ^ (r & 7)) * 8;
      gload_lds16(BT + (size_t)(col0 + r) * KDIM + k0 + c, &Bs[buf][p * 2048 + wuni]);
    }
  };

  constexpr int NT = (KDIM / 2) / 64;  // 16

  stage(kbase, 0);
  stage(kbase + 64, 1);
  asm volatile("s_waitcnt vmcnt(6)" ::: "memory");   // tile 0 landed, tile 1 in flight
  __syncthreads();

  int cur = 0;
  for (int t = 0; t < NT; ++t) {
    const int sb = (cur == 0) ? 2 : (cur - 1);       // (cur+2)%3
    if (t + 2 < NT) stage(kbase + (t + 2) * 64, sb);

    const short* __restrict__ Acur = As[cur];
    const short* __restrict__ Bcur = Bs[cur];
#pragma unroll
    for (int ks = 0; ks < 2; ++ks) {
      const int kk = ks * 32 + lk8;
      s16x8 a[2], b[4];
#pragma unroll
      for (int mi = 0; mi < 2; mi++) {
        int rr = wr * 32 + mi * 16 + lrow;
        int sidx = (rr * 64 + kk) ^ ((rr & 7) << 3);
        a[mi] = *(const s16x8*)(&Acur[sidx]);
      }
#pragma unroll
      for (int ni = 0; ni < 4; ni++) {
        int rr = wc * 64 + ni * 16 + lrow;
        int sidx = (rr * 64 + kk) ^ ((rr & 7) << 3);
        b[ni] = *(const s16x8*)(&Bcur[sidx]);
      }
      __builtin_amdgcn_s_setprio(1);
#pragma unroll
      for (int mi = 0; mi < 2; mi++)
#pragma unroll
        for (int ni = 0; ni < 4; ni++)
          acc[mi][ni] = __builtin_amdgcn_mfma_f32_16x16x32_bf16(a[mi], b[ni], acc[mi][ni], 0, 0, 0);
      __builtin_amdgcn_s_setprio(0);
    }

    if (t + 2 < NT) {
      asm volatile("s_waitcnt vmcnt(6)" ::: "memory");  // tile t+1 landed, t+2 in flight
    } else if (t + 1 < NT) {
      asm volatile("s_waitcnt vmcnt(0)" ::: "memory");  // tail: only t+1 outstanding
    }
    __syncthreads();
    cur = (cur == 2) ? 0 : (cur + 1);
  }

  float* __restrict__ P = ksplit ? P1 : P0;
#pragma unroll
  for (int mi = 0; mi < 2; mi++) {
#pragma unroll
    for (int ni = 0; ni < 4; ni++) {
      const int col = col0 + wc * 64 + ni * 16 + lrow;
      const int rbase = row0 + wr * 32 + mi * 16 + (l >> 4) * 4;
#pragma unroll
      for (int j = 0; j < 4; j++)
        P[(size_t)(rbase + j) * NDIM + col] = acc[mi][ni][j];
    }
  }
}

// ---------------- fused per-row epilogue: combine partials + g + gamma + update ----------------
// MODE 0: xproj = P0+P1+bias; z1 = 0.9*tanh(xproj); writes xproj, z1, zb
// MODE 1: g = tanh(P0+P1+xproj) - z; z2 = z + 0.9g; writes g, z2, zb
// MODE 2: g, gamma(row), anderson update; writes g, znew, zb
// MODE 3: g, gamma(row), anderson update; writes d_out only
template <int MODE>
__global__ __launch_bounds__(256) void rowfused_kernel(const float* __restrict__ P0,
                                                       const float* __restrict__ P1,
                                                       const float* __restrict__ xp_or_bias,
                                                       const float* __restrict__ z,
                                                       const float* __restrict__ zp,
                                                       const float* __restrict__ gp,
                                                       float* __restrict__ gout,
                                                       float* __restrict__ zout,
                                                       unsigned short* __restrict__ zbout,
                                                       float* __restrict__ xpout) {
  const int row = blockIdx.x;
  const int tid = threadIdx.x;
  const size_t b4 = (size_t)row * (NDIM / 4);
  __shared__ float sn[4], sd[4];
  __shared__ float sga;

  int vi[2] = {tid, tid + 256};
  f32x4 gv[2], znv[2], zv[2], zpv[2], gpv[2];
  float num = 0.f, den = 0.f;

#pragma unroll
  for (int h = 0; h < 2; h++) {
    const size_t q = b4 + vi[h];
    f32x4 p0 = ((const f32x4*)P0)[q];
    f32x4 p1 = ((const f32x4*)P1)[q];
    f32x4 xb;
    if (MODE == 0) xb = ((const f32x4*)xp_or_bias)[vi[h]];   // bias (row-invariant)
    else xb = ((const f32x4*)xp_or_bias)[q];                 // xproj
    if (MODE != 0) zv[h] = ((const f32x4*)z)[q];
    if (MODE >= 2) {
      zpv[h] = ((const f32x4*)zp)[q];
      gpv[h] = ((const f32x4*)gp)[q];
    }
#pragma unroll
    for (int j = 0; j < 4; j++) {
      const float s = p0[j] + p1[j] + xb[j];
      if (MODE == 0) {
        const float z1 = BETAC * tanhf(s);
        gv[h][j] = s;      // xproj value to store
        znv[h][j] = z1;
      } else {
        const float g = tanhf(s) - zv[h][j];
        gv[h][j] = g;
        if (MODE == 1) znv[h][j] = zv[h][j] + BETAC * g;
        else {
          const float dg = g - gpv[h][j];
          num += dg * g;
          den += dg * dg;
        }
      }
    }
  }

  if (MODE >= 2) {
#pragma unroll
    for (int off = 32; off > 0; off >>= 1) {
      num += __shfl_down(num, off);
      den += __shfl_down(den, off);
    }
    if ((tid & 63) == 0) { sn[tid >> 6] = num; sd[tid >> 6] = den; }
    __syncthreads();
    if (tid == 0)
      sga = (sn[0] + sn[1] + sn[2] + sn[3]) / (sd[0] + sd[1] + sd[2] + sd[3] + LAMC);
    __syncthreads();
    const float ga = sga;
#pragma unroll
    for (int h = 0; h < 2; h++)
#pragma unroll
      for (int j = 0; j < 4; j++)
        znv[h][j] = zv[h][j] + BETAC * gv[h][j]
                  - ga * ((zv[h][j] - zpv[h][j]) + BETAC * (gv[h][j] - gpv[h][j]));
  }

#pragma unroll
  for (int h = 0; h < 2; h++) {
    const size_t q = b4 + vi[h];
    if (MODE == 0) ((f32x4*)xpout)[q] = gv[h];
    if (MODE == 1 || MODE == 2) ((f32x4*)gout)[q] = gv[h];
    ((f32x4*)zout)[q] = znv[h];
    if (MODE != 3) {
      ushort4 o;
      o.x = f2bf(znv[h][0]); o.y = f2bf(znv[h][1]);
      o.z = f2bf(znv[h][2]); o.w = f2bf(znv[h][3]);
      ((ushort4*)zbout)[q] = o;
    }
  }
}

extern "C" void kernel_launch(void* const* d_in, const int* in_sizes, int n_in,
                              void* d_out, int out_size, void* d_ws, size_t ws_size,
                              hipStream_t stream) {
  const float* x = (const float*)d_in[0];
  const float* Wz = (const float*)d_in[1];
  const float* Wx = (const float*)d_in[2];
  const float* bias = (const float*)d_in[3];

  const size_t MN = (size_t)MDIM * NDIM;
  const size_t KN = (size_t)KDIM * NDIM;
  char* ws = (char*)d_ws;
  size_t off = 0;
  auto alloc = [&](size_t bytes) -> void* {
    void* p = ws + off;
    off += (bytes + 255) & ~(size_t)255;
    return p;
  };
  unsigned short* WzT = (unsigned short*)alloc(KN * 2);
  unsigned short* WxT = (unsigned short*)alloc(KN * 2);
  unsigned short* xb = (unsigned short*)alloc(MN * 2);
  float* xproj = (float*)alloc(MN * 4);
  float* zA = (float*)alloc(MN * 4);
  float* zB = (float*)alloc(MN * 4);
  float* gA = (float*)alloc(MN * 4);
  float* gB = (float*)alloc(MN * 4);
  unsigned short* zb16 = (unsigned short*)alloc(MN * 2);
  float* P0 = (float*)alloc(MN * 4);
  float* P1 = (float*)alloc(MN * 4);
  (void)ws_size;

  const dim3 tb(32, 8);
  const dim3 pgrid(NDIM / 32, KDIM / 32, 3);
  const int ggrid = 512;   // 16n x 16m x 2ks, XCD-swizzled in-kernel

  prep_kernel<<<pgrid, tb, 0, stream>>>(Wz, Wx, WzT, WxT, x, xb);

  // iter 0: x_proj = x@Wx + b ; z1 = 0.9*tanh(x_proj)
  gemm_split_kernel<<<ggrid, 256, 0, stream>>>(xb, WxT, P0, P1);
  rowfused_kernel<0><<<MDIM, 256, 0, stream>>>(P0, P1, bias, nullptr, nullptr, nullptr,
                                               nullptr, zA, zb16, xproj);

  float* zc = zA;
  float* zp = zB;
  float* gc = gA;
  float* gp = gB;

  // iter 1: simple update
  gemm_split_kernel<<<ggrid, 256, 0, stream>>>(zb16, WzT, P0, P1);
  rowfused_kernel<1><<<MDIM, 256, 0, stream>>>(P0, P1, xproj, zc, nullptr, nullptr,
                                               gc, zp, zb16, nullptr);
  { float* t = zc; zc = zp; zp = t; }   // zc=z2, zp=z1
  { float* t = gc; gc = gp; gp = t; }   // gp=g1

  // iters 2..4: anderson updates
  for (int it = 2; it < 5; ++it) {
    gemm_split_kernel<<<ggrid, 256, 0, stream>>>(zb16, WzT, P0, P1);
    rowfused_kernel<2><<<MDIM, 256, 0, stream>>>(P0, P1, xproj, zc, zp, gp,
                                                 gc, zp, zb16, nullptr);
    { float* t = zc; zc = zp; zp = t; }
    { float* t = gc; gc = gp; gp = t; }
  }

  // iter 5: final anderson update straight to d_out
  gemm_split_kernel<<<ggrid, 256, 0, stream>>>(zb16, WzT, P0, P1);
  rowfused_kernel<3><<<MDIM, 256, 0, stream>>>(P0, P1, xproj, zc, zp, gp,
                                               nullptr, (float*)d_out, nullptr, nullptr);
}